// Round 7
// baseline (654.549 us; speedup 1.0000x reference)
//
#include <hip/hip_runtime.h>
#include <hip/hip_bf16.h>
#include <math.h>

#define NN 50000
#define FF 256
#define HH 64
#define LL 8
#define EE 1600000
#define CC 40

#define RSZ 6250                 // dst nodes per XCD range (50000/8)
#define CHUNK_E 8192             // edges per work chunk
#define NCHUNK ((EE + CHUNK_E - 1) / CHUNK_E)

using short8 = __attribute__((ext_vector_type(8))) short;
using f32x4  = __attribute__((ext_vector_type(4))) float;

static __device__ __forceinline__ unsigned short f2b(float f) {
    union { __hip_bfloat16 h; unsigned short u; } cv;
    cv.h = __float2bfloat16(f);
    return cv.u;
}
static __device__ __forceinline__ float b2f(unsigned short u) {
    return __uint_as_float((unsigned)u << 16);
}

// ---------------- edge pack: {dst | src<<16, bf16(w)} ----------------
__global__ void k_pack(const int* __restrict__ src, const int* __restrict__ dst,
                       const float* __restrict__ w, uint2* __restrict__ epack) {
    int e = blockIdx.x * 256 + threadIdx.x;
    if (e < EE) {
        epack[e] = make_uint2((unsigned)dst[e] | ((unsigned)src[e] << 16),
                              (unsigned)f2b(w[e]));
    }
}

__global__ void k_hist(const uint2* __restrict__ epack, int* __restrict__ cnt) {
    int e = blockIdx.x * 256 + threadIdx.x;
    if (e < EE) atomicAdd(&cnt[epack[e].x & 0xFFFFu], 1);
}

__global__ void k_scanA(const int* __restrict__ cnt, int* __restrict__ incl, int* __restrict__ bsum) {
    __shared__ int buf[1024];
    int i = blockIdx.x * 1024 + threadIdx.x;
    int v = (i < NN) ? cnt[i] : 0;
    buf[threadIdx.x] = v;
    __syncthreads();
    for (int off = 1; off < 1024; off <<= 1) {
        int t = (threadIdx.x >= off) ? buf[threadIdx.x - off] : 0;
        __syncthreads();
        buf[threadIdx.x] += t;
        __syncthreads();
    }
    if (i < NN) incl[i] = buf[threadIdx.x];
    if (threadIdx.x == 1023) bsum[blockIdx.x] = buf[1023];
}

__global__ void k_scanB(int* __restrict__ bsum) {
    int t = threadIdx.x;
    int vin = (t < 49) ? bsum[t] : 0;
    int v = vin;
    for (int off = 1; off < 64; off <<= 1) {
        int u = __shfl_up(v, off);
        if (t >= off) v += u;
    }
    if (t < 49) bsum[t] = v - vin;  // exclusive
}

__global__ void k_scanC(const int* __restrict__ cnt, const int* __restrict__ incl,
                        const int* __restrict__ bsum, int* __restrict__ row_ptr,
                        int* __restrict__ cursor) {
    int i = blockIdx.x * 1024 + threadIdx.x;
    if (i < NN) {
        int e = incl[i] - cnt[i] + bsum[blockIdx.x];
        row_ptr[i] = e;
        cursor[i] = e;
    }
    if (i == 0) row_ptr[NN] = EE;
}

// ---------------- XCD-local scatter ----------------
// Each block learns its physical XCD; blocks drain work chunks for their own
// dst range first (writes stay in the local L2 and combine into full lines),
// then steal remaining ranges (correctness never depends on XCD mapping).
__global__ void k_scatX(const uint2* __restrict__ epack, int* __restrict__ cursor,
                        int* __restrict__ ticket, unsigned* __restrict__ pay) {
    int myx;
    asm("s_getreg_b32 %0, hwreg(HW_REG_XCC_ID)" : "=s"(myx));
    myx &= 7;
    __shared__ int s_chunk;
    for (int pass = 0; pass < 8; ++pass) {
        int r = (myx + pass) & 7;
        unsigned rlo = (unsigned)(r * RSZ), rhi = rlo + RSZ;
        while (true) {
            if (threadIdx.x == 0) s_chunk = atomicAdd(&ticket[r], 1);
            __syncthreads();
            int c = s_chunk;
            __syncthreads();
            if (c >= NCHUNK) break;
            int e0 = c * CHUNK_E + threadIdx.x;
#pragma unroll 4
            for (int i = 0; i < CHUNK_E / 256; ++i) {
                int e = e0 + i * 256;
                if (e < EE) {
                    uint2 pk = epack[e];
                    unsigned d = pk.x & 0xFFFFu;
                    if (d >= rlo && d < rhi) {
                        int p = atomicAdd(&cursor[d], 1);
                        pay[p] = (pk.x & 0xFFFF0000u) | pk.y;  // src<<16 | bf16(w)
                    }
                }
            }
        }
    }
}

// ---------------- initial projection via MFMA: h0 = relu(x @ W0 + b0) ----------------
__global__ __launch_bounds__(512) void k_h0m(const float* __restrict__ x,
                                             const float* __restrict__ W0,
                                             const float* __restrict__ b0,
                                             float* __restrict__ h0f,
                                             unsigned short* __restrict__ h0b) {
    __shared__ __align__(16) __hip_bfloat16 ax[256][72];
    __shared__ __align__(16) __hip_bfloat16 bw[64][72];

    int tid = threadIdx.x;
    int lane = tid & 63;
    int w = tid >> 6;
    int nbase = blockIdx.x * 256;

    f32x4 acc[2][4];
#pragma unroll
    for (int nf = 0; nf < 2; ++nf)
#pragma unroll
        for (int cf = 0; cf < 4; ++cf) acc[nf][cf] = (f32x4){0.f, 0.f, 0.f, 0.f};

    int arow = w * 32 + (lane & 15);
    int kq = (lane >> 4) * 8;

    for (int kc = 0; kc < 4; ++kc) {
        __syncthreads();
#pragma unroll
        for (int p = 0; p < 8; ++p) {
            int q = p * 512 + tid;
            int r = q >> 4, cq = q & 15;
            int node = nbase + r;
            float4 v = {0.f, 0.f, 0.f, 0.f};
            if (node < NN) v = *(const float4*)&x[(size_t)node * FF + kc * 64 + cq * 4];
            __hip_bfloat16* d = &ax[r][cq * 4];
            d[0] = __float2bfloat16(v.x);
            d[1] = __float2bfloat16(v.y);
            d[2] = __float2bfloat16(v.z);
            d[3] = __float2bfloat16(v.w);
        }
#pragma unroll
        for (int u = 0; u < 8; ++u) {
            int k = (tid >> 6) * 8 + u;
            float v = W0[(size_t)(kc * 64 + k) * HH + lane];
            bw[lane][k] = __float2bfloat16(v);
        }
        __syncthreads();
#pragma unroll
        for (int ks = 0; ks < 2; ++ks) {
            short8 a0 = *(const short8*)&ax[arow][ks * 32 + kq];
            short8 a1 = *(const short8*)&ax[arow + 16][ks * 32 + kq];
#pragma unroll
            for (int cf = 0; cf < 4; ++cf) {
                short8 b = *(const short8*)&bw[cf * 16 + (lane & 15)][ks * 32 + kq];
                acc[0][cf] = __builtin_amdgcn_mfma_f32_16x16x32_bf16(a0, b, acc[0][cf], 0, 0, 0);
                acc[1][cf] = __builtin_amdgcn_mfma_f32_16x16x32_bf16(a1, b, acc[1][cf], 0, 0, 0);
            }
        }
    }

#pragma unroll
    for (int nf = 0; nf < 2; ++nf) {
#pragma unroll
        for (int cf = 0; cf < 4; ++cf) {
            int c = cf * 16 + (lane & 15);
            float bias = b0[c];
#pragma unroll
            for (int r = 0; r < 4; ++r) {
                int node = nbase + w * 32 + nf * 16 + ((lane >> 4) << 2) + r;
                if (node < NN) {
                    float v = fmaxf(acc[nf][cf][r] + bias, 0.f);
                    h0f[(size_t)node * HH + c] = v;
                    h0b[(size_t)node * HH + c] = f2b(v);
                }
            }
        }
    }
}

// ---------------- fused layer: SpMM(bf16 gather) + blend + matvec + relu ----------------
// one wave per 4 nodes; lane = feature channel. Zero-padded 16-deep gather
// pipeline (no serial tail), 4-way split accumulators.
__global__ __launch_bounds__(256, 8) void k_layer(
        const unsigned short* __restrict__ hin, const float* __restrict__ h0,
        const int* __restrict__ row_ptr, const unsigned* __restrict__ pay,
        const float* __restrict__ Wl, float beta,
        unsigned short* __restrict__ hout) {
    int lane = threadIdx.x & 63;
    int n0 = (blockIdx.x * 4 + (threadIdx.x >> 6)) * 4;

    float hmix[4];
#pragma unroll
    for (int u = 0; u < 4; ++u) {
        int n = n0 + u;
        int rb = row_ptr[n], re = row_ptr[n + 1];
        float a0 = 0.f, a1 = 0.f, a2 = 0.f, a3 = 0.f;
        for (int base = rb; base < re; base += 64) {
            int idx = base + lane;
            unsigned pv = (idx < re) ? pay[idx] : 0u;  // pad lanes: src=0, w=+0
            int ecnt = min(64, re - base);
            for (int k = 0; k < ecnt; k += 16) {
                float vv[16], ws[16];
#pragma unroll
                for (int t = 0; t < 16; t++) {
                    unsigned pk = (unsigned)__builtin_amdgcn_readlane((int)pv, k + t);
                    ws[t] = __uint_as_float((pk & 0xFFFFu) << 16);
                    vv[t] = b2f(hin[(size_t)(pk >> 16) * HH + lane]);
                }
#pragma unroll
                for (int t = 0; t < 16; t += 4) {
                    a0 = fmaf(ws[t + 0], vv[t + 0], a0);
                    a1 = fmaf(ws[t + 1], vv[t + 1], a1);
                    a2 = fmaf(ws[t + 2], vv[t + 2], a2);
                    a3 = fmaf(ws[t + 3], vv[t + 3], a3);
                }
            }
        }
        float acc = (a0 + a1) + (a2 + a3);
        hmix[u] = fmaf(0.9f, acc, 0.1f * h0[(size_t)n * HH + lane]);
    }

    int hb[4];
#pragma unroll
    for (int u = 0; u < 4; ++u) hb[u] = __float_as_int(hmix[u]);
    float a2[4] = {0.f, 0.f, 0.f, 0.f};
#pragma unroll
    for (int j = 0; j < HH; j++) {
        float wr = Wl[j * HH + lane];
#pragma unroll
        for (int u = 0; u < 4; ++u) {
            float hj = __int_as_float(__builtin_amdgcn_readlane(hb[u], j));
            a2[u] = fmaf(hj, wr, a2[u]);
        }
    }
#pragma unroll
    for (int u = 0; u < 4; ++u) {
        float outv = (1.f - beta) * hmix[u] + beta * a2[u];
        hout[(size_t)(n0 + u) * HH + lane] = f2b(fmaxf(outv, 0.f));
    }
}

// ---------------- head via MFMA (h input is bf16) ----------------
__global__ __launch_bounds__(512) void k_head(const unsigned short* __restrict__ h,
                                              const float* __restrict__ W2,
                                              const float* __restrict__ b2,
                                              float* __restrict__ out) {
    __shared__ __align__(16) unsigned short hb[256][72];
    __shared__ float hf[256][65];
    __shared__ __align__(16) __hip_bfloat16 Bc[8][48][72];

    int tid = threadIdx.x;
    int lane = tid & 63;
    int w = tid >> 6;
    int nbase = blockIdx.x * 256;

#pragma unroll
    for (int p = 0; p < 32; ++p) {
        int idx = p * 512 + tid;
        int r = idx >> 6, c = idx & 63;
        int node = nbase + r;
        unsigned short raw = (node < NN) ? h[(size_t)node * HH + c] : 0;
        hf[r][c] = b2f(raw);
        hb[r][c] = raw;
    }
    for (int p = tid; p < 8 * 8 * 64; p += 512) {
        int il = p >> 9;
        int c = 40 + ((p >> 6) & 7);
        int j = p & 63;
        Bc[il][c][j] = __float2bfloat16(0.f);
    }

    f32x4 acc[2][3];
#pragma unroll
    for (int nf = 0; nf < 2; ++nf)
#pragma unroll
        for (int ct = 0; ct < 3; ++ct) acc[nf][ct] = (f32x4){0.f, 0.f, 0.f, 0.f};

    const f32x4 zf = (f32x4){0.f, 0.f, 0.f, 0.f};
    int arow0 = w * 32 + (lane & 15);
    int kq = (lane >> 4) * 8;
    int rb4 = w * 32 + ((lane >> 4) << 2);

    for (int ic = 0; ic < 8; ++ic) {
        __syncthreads();
#pragma unroll
        for (int p = 0; p < 10; ++p) {
            int q = p * 512 + tid;
            int cq = q % 10;
            int jj = (q / 10) & 63;
            int il = q / 640;
            const float4 v = *(const float4*)&W2[(((size_t)(ic * 8 + il) * 64 + jj) * CC) + cq * 4];
            Bc[il][cq * 4 + 0][jj] = __float2bfloat16(v.x);
            Bc[il][cq * 4 + 1][jj] = __float2bfloat16(v.y);
            Bc[il][cq * 4 + 2][jj] = __float2bfloat16(v.z);
            Bc[il][cq * 4 + 3][jj] = __float2bfloat16(v.w);
        }
        __syncthreads();

#pragma unroll
        for (int il = 0; il < 8; ++il) {
            int ii = ic * 8 + il;
            short8 a0k0 = *(const short8*)&hb[arow0][kq];
            short8 a0k1 = *(const short8*)&hb[arow0][32 + kq];
            short8 a1k0 = *(const short8*)&hb[arow0 + 16][kq];
            short8 a1k1 = *(const short8*)&hb[arow0 + 16][32 + kq];
            short8 b0k0 = *(const short8*)&Bc[il][(lane & 15)][kq];
            short8 b0k1 = *(const short8*)&Bc[il][(lane & 15)][32 + kq];
            short8 b1k0 = *(const short8*)&Bc[il][16 + (lane & 15)][kq];
            short8 b1k1 = *(const short8*)&Bc[il][16 + (lane & 15)][32 + kq];
            short8 b2k0 = *(const short8*)&Bc[il][32 + (lane & 15)][kq];
            short8 b2k1 = *(const short8*)&Bc[il][32 + (lane & 15)][32 + kq];
            float s0[4], s1[4];
#pragma unroll
            for (int r = 0; r < 4; ++r) {
                s0[r] = hf[rb4 + r][ii];
                s1[r] = hf[rb4 + 16 + r][ii];
            }
            f32x4 t;
            t = __builtin_amdgcn_mfma_f32_16x16x32_bf16(a0k0, b0k0, zf, 0, 0, 0);
            t = __builtin_amdgcn_mfma_f32_16x16x32_bf16(a0k1, b0k1, t, 0, 0, 0);
#pragma unroll
            for (int r = 0; r < 4; ++r) acc[0][0][r] = fmaf(s0[r], t[r], acc[0][0][r]);
            t = __builtin_amdgcn_mfma_f32_16x16x32_bf16(a0k0, b1k0, zf, 0, 0, 0);
            t = __builtin_amdgcn_mfma_f32_16x16x32_bf16(a0k1, b1k1, t, 0, 0, 0);
#pragma unroll
            for (int r = 0; r < 4; ++r) acc[0][1][r] = fmaf(s0[r], t[r], acc[0][1][r]);
            t = __builtin_amdgcn_mfma_f32_16x16x32_bf16(a0k0, b2k0, zf, 0, 0, 0);
            t = __builtin_amdgcn_mfma_f32_16x16x32_bf16(a0k1, b2k1, t, 0, 0, 0);
#pragma unroll
            for (int r = 0; r < 4; ++r) acc[0][2][r] = fmaf(s0[r], t[r], acc[0][2][r]);
            t = __builtin_amdgcn_mfma_f32_16x16x32_bf16(a1k0, b0k0, zf, 0, 0, 0);
            t = __builtin_amdgcn_mfma_f32_16x16x32_bf16(a1k1, b0k1, t, 0, 0, 0);
#pragma unroll
            for (int r = 0; r < 4; ++r) acc[1][0][r] = fmaf(s1[r], t[r], acc[1][0][r]);
            t = __builtin_amdgcn_mfma_f32_16x16x32_bf16(a1k0, b1k0, zf, 0, 0, 0);
            t = __builtin_amdgcn_mfma_f32_16x16x32_bf16(a1k1, b1k1, t, 0, 0, 0);
#pragma unroll
            for (int r = 0; r < 4; ++r) acc[1][1][r] = fmaf(s1[r], t[r], acc[1][1][r]);
            t = __builtin_amdgcn_mfma_f32_16x16x32_bf16(a1k0, b2k0, zf, 0, 0, 0);
            t = __builtin_amdgcn_mfma_f32_16x16x32_bf16(a1k1, b2k1, t, 0, 0, 0);
#pragma unroll
            for (int r = 0; r < 4; ++r) acc[1][2][r] = fmaf(s1[r], t[r], acc[1][2][r]);
        }
    }

#pragma unroll
    for (int nf = 0; nf < 2; ++nf) {
#pragma unroll
        for (int ct = 0; ct < 3; ++ct) {
            int c = ct * 16 + (lane & 15);
            if (c < CC) {
                float bias = b2[c];
#pragma unroll
                for (int r = 0; r < 4; ++r) {
                    int node = nbase + w * 32 + nf * 16 + ((lane >> 4) << 2) + r;
                    if (node < NN) out[(size_t)node * CC + c] = acc[nf][ct][r] + bias;
                }
            }
        }
    }
}

// ---------------- log_softmax in place, wave per node ----------------
__global__ void k_lsm(float* __restrict__ out) {
    int lane = threadIdx.x & 63;
    int n = (blockIdx.x * 256 + threadIdx.x) >> 6;
    if (n >= NN) return;
    float x = (lane < CC) ? out[(size_t)n * CC + lane] : -INFINITY;
    float m = x;
    for (int off = 32; off; off >>= 1) m = fmaxf(m, __shfl_xor(m, off));
    float e = (lane < CC) ? expf(x - m) : 0.f;
    float s = e;
    for (int off = 32; off; off >>= 1) s += __shfl_xor(s, off);
    float lse = m + logf(s);
    if (lane < CC) out[(size_t)n * CC + lane] = x - lse;
}

extern "C" void kernel_launch(void* const* d_in, const int* in_sizes, int n_in,
                              void* d_out, int out_size, void* d_ws, size_t ws_size,
                              hipStream_t stream) {
    const float* x  = (const float*)d_in[0];
    const int*   ei = (const int*)d_in[1];
    const float* ew = (const float*)d_in[2];
    const float* W0 = (const float*)d_in[3];
    const float* b0 = (const float*)d_in[4];
    const float* Wl = (const float*)d_in[5];
    const float* W2 = (const float*)d_in[6];
    const float* b2 = (const float*)d_in[7];
    float* out = (float*)d_out;

    char* ws = (char*)d_ws;
    size_t off = 0;
    auto alloc = [&](size_t b) { size_t o = off; off += (b + 255) & ~(size_t)255; return o; };
    float*          h0f = (float*)(ws + alloc((size_t)NN * HH * 4));
    unsigned short* h0b = (unsigned short*)(ws + alloc((size_t)NN * HH * 2));
    unsigned short* hA  = (unsigned short*)(ws + alloc((size_t)NN * HH * 2));
    unsigned short* hB  = (unsigned short*)(ws + alloc((size_t)NN * HH * 2));
    int*      cnt     = (int*)(ws + alloc((size_t)NN * 4));
    int*      incl    = (int*)(ws + alloc((size_t)NN * 4));
    int*      bsum    = (int*)(ws + alloc(256));
    int*      row_ptr = (int*)(ws + alloc((size_t)(NN + 1) * 4));
    int*      cursor  = (int*)(ws + alloc((size_t)NN * 4));
    int*      ticket  = (int*)(ws + alloc(64));
    uint2*    epack   = (uint2*)(ws + alloc((size_t)EE * 8));
    unsigned* pay     = (unsigned*)(ws + alloc((size_t)EE * 4));

    const int* srcp = ei;
    const int* dstp = ei + EE;

    hipMemsetAsync(cnt, 0, (size_t)NN * 4, stream);
    hipMemsetAsync(ticket, 0, 64, stream);
    k_pack<<<(EE + 255) / 256, 256, 0, stream>>>(srcp, dstp, ew, epack);
    k_hist<<<(EE + 255) / 256, 256, 0, stream>>>(epack, cnt);
    k_scanA<<<49, 1024, 0, stream>>>(cnt, incl, bsum);
    k_scanB<<<1, 64, 0, stream>>>(bsum);
    k_scanC<<<49, 1024, 0, stream>>>(cnt, incl, bsum, row_ptr, cursor);
    k_scatX<<<1024, 256, 0, stream>>>(epack, cursor, ticket, pay);

    k_h0m<<<196, 512, 0, stream>>>(x, W0, b0, h0f, h0b);

    const unsigned short* hin = h0b;
    unsigned short* ho = hA;
    for (int l = 0; l < LL; l++) {
        float beta = (float)log(0.5 / (double)(l + 1) + 1.0);
        k_layer<<<3125, 256, 0, stream>>>(hin, h0f, row_ptr, pay,
                                          Wl + (size_t)l * HH * HH, beta, ho);
        hin = ho;
        ho = (ho == hA) ? hB : hA;
    }

    k_head<<<196, 512, 0, stream>>>(hin, W2, b2, out);
    k_lsm<<<(NN * 64 + 255) / 256, 256, 0, stream>>>(out);
}

// Round 8
// 624.914 us; speedup vs baseline: 1.0474x; 1.0474x over previous
//
#include <hip/hip_runtime.h>
#include <hip/hip_bf16.h>
#include <math.h>

#define NN 50000
#define FF 256
#define HH 64
#define LL 8
#define EE 1600000
#define CC 40

using short8 = __attribute__((ext_vector_type(8))) short;
using f32x4  = __attribute__((ext_vector_type(4))) float;

static __device__ __forceinline__ unsigned short f2b(float f) {
    union { __hip_bfloat16 h; unsigned short u; } cv;
    cv.h = __float2bfloat16(f);
    return cv.u;
}
static __device__ __forceinline__ float b2f(unsigned short u) {
    return __uint_as_float((unsigned)u << 16);
}

// ---------------- CSR build ----------------

__global__ void k_hist(const int* __restrict__ dst, int* __restrict__ cnt) {
    int e = blockIdx.x * 256 + threadIdx.x;
    if (e < EE) atomicAdd(&cnt[dst[e]], 1);
}

__global__ void k_scanA(const int* __restrict__ cnt, int* __restrict__ incl, int* __restrict__ bsum) {
    __shared__ int buf[1024];
    int i = blockIdx.x * 1024 + threadIdx.x;
    int v = (i < NN) ? cnt[i] : 0;
    buf[threadIdx.x] = v;
    __syncthreads();
    for (int off = 1; off < 1024; off <<= 1) {
        int t = (threadIdx.x >= off) ? buf[threadIdx.x - off] : 0;
        __syncthreads();
        buf[threadIdx.x] += t;
        __syncthreads();
    }
    if (i < NN) incl[i] = buf[threadIdx.x];
    if (threadIdx.x == 1023) bsum[blockIdx.x] = buf[1023];
}

__global__ void k_scanB(int* __restrict__ bsum) {
    int t = threadIdx.x;
    int vin = (t < 49) ? bsum[t] : 0;
    int v = vin;
    for (int off = 1; off < 64; off <<= 1) {
        int u = __shfl_up(v, off);
        if (t >= off) v += u;
    }
    if (t < 49) bsum[t] = v - vin;  // exclusive
}

__global__ void k_scanC(const int* __restrict__ cnt, const int* __restrict__ incl,
                        const int* __restrict__ bsum, int* __restrict__ row_ptr,
                        int* __restrict__ cursor) {
    int i = blockIdx.x * 1024 + threadIdx.x;
    if (i < NN) {
        int e = incl[i] - cnt[i] + bsum[blockIdx.x];
        row_ptr[i] = e;
        cursor[i] = e;
    }
    if (i == 0) row_ptr[NN] = EE;
}

// pay word: src (16 high bits) | bf16(w) (16 low bits)
__global__ void k_scatter(const int* __restrict__ src, const int* __restrict__ dst,
                          const float* __restrict__ w, int* __restrict__ cursor,
                          unsigned* __restrict__ pay) {
    int e = blockIdx.x * 256 + threadIdx.x;
    if (e < EE) {
        int d = dst[e];
        int p = atomicAdd(&cursor[d], 1);
        pay[p] = ((unsigned)src[e] << 16) | (unsigned)f2b(w[e]);
    }
}

// ---------------- initial projection via MFMA: h0 = relu(x @ W0 + b0) ----------------
__global__ __launch_bounds__(512) void k_h0m(const float* __restrict__ x,
                                             const float* __restrict__ W0,
                                             const float* __restrict__ b0,
                                             float* __restrict__ h0f,
                                             unsigned short* __restrict__ h0b) {
    __shared__ __align__(16) __hip_bfloat16 ax[256][72];
    __shared__ __align__(16) __hip_bfloat16 bw[64][72];

    int tid = threadIdx.x;
    int lane = tid & 63;
    int w = tid >> 6;
    int nbase = blockIdx.x * 256;

    f32x4 acc[2][4];
#pragma unroll
    for (int nf = 0; nf < 2; ++nf)
#pragma unroll
        for (int cf = 0; cf < 4; ++cf) acc[nf][cf] = (f32x4){0.f, 0.f, 0.f, 0.f};

    int arow = w * 32 + (lane & 15);
    int kq = (lane >> 4) * 8;

    for (int kc = 0; kc < 4; ++kc) {
        __syncthreads();
#pragma unroll
        for (int p = 0; p < 8; ++p) {
            int q = p * 512 + tid;
            int r = q >> 4, cq = q & 15;
            int node = nbase + r;
            float4 v = {0.f, 0.f, 0.f, 0.f};
            if (node < NN) v = *(const float4*)&x[(size_t)node * FF + kc * 64 + cq * 4];
            __hip_bfloat16* d = &ax[r][cq * 4];
            d[0] = __float2bfloat16(v.x);
            d[1] = __float2bfloat16(v.y);
            d[2] = __float2bfloat16(v.z);
            d[3] = __float2bfloat16(v.w);
        }
#pragma unroll
        for (int u = 0; u < 8; ++u) {
            int k = (tid >> 6) * 8 + u;
            float v = W0[(size_t)(kc * 64 + k) * HH + lane];
            bw[lane][k] = __float2bfloat16(v);
        }
        __syncthreads();
#pragma unroll
        for (int ks = 0; ks < 2; ++ks) {
            short8 a0 = *(const short8*)&ax[arow][ks * 32 + kq];
            short8 a1 = *(const short8*)&ax[arow + 16][ks * 32 + kq];
#pragma unroll
            for (int cf = 0; cf < 4; ++cf) {
                short8 b = *(const short8*)&bw[cf * 16 + (lane & 15)][ks * 32 + kq];
                acc[0][cf] = __builtin_amdgcn_mfma_f32_16x16x32_bf16(a0, b, acc[0][cf], 0, 0, 0);
                acc[1][cf] = __builtin_amdgcn_mfma_f32_16x16x32_bf16(a1, b, acc[1][cf], 0, 0, 0);
            }
        }
    }

#pragma unroll
    for (int nf = 0; nf < 2; ++nf) {
#pragma unroll
        for (int cf = 0; cf < 4; ++cf) {
            int c = cf * 16 + (lane & 15);
            float bias = b0[c];
#pragma unroll
            for (int r = 0; r < 4; ++r) {
                int node = nbase + w * 32 + nf * 16 + ((lane >> 4) << 2) + r;
                if (node < NN) {
                    float v = fmaxf(acc[nf][cf][r] + bias, 0.f);
                    h0f[(size_t)node * HH + c] = v;
                    h0b[(size_t)node * HH + c] = f2b(v);
                }
            }
        }
    }
}

// ---------------- fused layer: paired-edge bf16x2 SpMM + blend + matvec + relu ----------------
// one wave per 4 nodes. Lanes 0-31 process even-slot edges, lanes 32-63 odd-slot
// edges; each lane gathers bf16x2 (channels 2j, 2j+1). Halves vmem instr count.
__global__ __launch_bounds__(256, 8) void k_layer(
        const unsigned short* __restrict__ hin, const float* __restrict__ h0,
        const int* __restrict__ row_ptr, const unsigned* __restrict__ pay,
        const float* __restrict__ Wl, float beta,
        unsigned short* __restrict__ hout) {
    int lane = threadIdx.x & 63;
    int half = lane >> 5;
    int j = lane & 31;                 // channel pair (2j, 2j+1)
    int n0 = (blockIdx.x * 4 + (threadIdx.x >> 6)) * 4;

    const unsigned* __restrict__ hin32 = (const unsigned*)hin;

    float hmix[4];
#pragma unroll
    for (int u = 0; u < 4; ++u) {
        int n = n0 + u;
        int rb = row_ptr[n], re = row_ptr[n + 1];
        float ax0 = 0.f, ay0 = 0.f, ax1 = 0.f, ay1 = 0.f;
        for (int base = rb; base < re; base += 64) {
            int idx = base + lane;
            unsigned pv = (idx < re) ? pay[idx] : 0u;  // pad: src=0, w=+0
            int ecnt = min(64, re - base);
            for (int k = 0; k < ecnt; k += 8) {
                unsigned pk[8];
#pragma unroll
                for (int t = 0; t < 8; t++)
                    pk[t] = (unsigned)__builtin_amdgcn_readlane((int)pv, k + t);
                unsigned m0 = half ? pk[1] : pk[0];
                unsigned m1 = half ? pk[3] : pk[2];
                unsigned m2 = half ? pk[5] : pk[4];
                unsigned m3 = half ? pk[7] : pk[6];
                unsigned u0 = hin32[(size_t)(m0 >> 16) * 32 + j];
                unsigned u1 = hin32[(size_t)(m1 >> 16) * 32 + j];
                unsigned u2 = hin32[(size_t)(m2 >> 16) * 32 + j];
                unsigned u3 = hin32[(size_t)(m3 >> 16) * 32 + j];
                float w0 = __uint_as_float((m0 & 0xFFFFu) << 16);
                float w1 = __uint_as_float((m1 & 0xFFFFu) << 16);
                float w2 = __uint_as_float((m2 & 0xFFFFu) << 16);
                float w3 = __uint_as_float((m3 & 0xFFFFu) << 16);
                ax0 = fmaf(w0, __uint_as_float(u0 << 16), ax0);
                ay0 = fmaf(w0, __uint_as_float(u0 & 0xFFFF0000u), ay0);
                ax1 = fmaf(w1, __uint_as_float(u1 << 16), ax1);
                ay1 = fmaf(w1, __uint_as_float(u1 & 0xFFFF0000u), ay1);
                ax0 = fmaf(w2, __uint_as_float(u2 << 16), ax0);
                ay0 = fmaf(w2, __uint_as_float(u2 & 0xFFFF0000u), ay0);
                ax1 = fmaf(w3, __uint_as_float(u3 << 16), ax1);
                ay1 = fmaf(w3, __uint_as_float(u3 & 0xFFFF0000u), ay1);
            }
        }
        float ax = ax0 + ax1, ay = ay0 + ay1;
        ax += __shfl_xor(ax, 32);       // combine even/odd halves
        ay += __shfl_xor(ay, 32);
        // redistribute: lane c wants channel c from lane c>>1 (x even / y odd)
        float vx = __shfl(ax, lane >> 1);
        float vy = __shfl(ay, lane >> 1);
        float acc = (lane & 1) ? vy : vx;
        hmix[u] = fmaf(0.9f, acc, 0.1f * h0[(size_t)n * HH + lane]);
    }

    int hb[4];
#pragma unroll
    for (int u = 0; u < 4; ++u) hb[u] = __float_as_int(hmix[u]);
    float a2[4] = {0.f, 0.f, 0.f, 0.f};
#pragma unroll
    for (int jj = 0; jj < HH; jj++) {
        float wr = Wl[jj * HH + lane];
#pragma unroll
        for (int u = 0; u < 4; ++u) {
            float hj = __int_as_float(__builtin_amdgcn_readlane(hb[u], jj));
            a2[u] = fmaf(hj, wr, a2[u]);
        }
    }
#pragma unroll
    for (int u = 0; u < 4; ++u) {
        float outv = (1.f - beta) * hmix[u] + beta * a2[u];
        hout[(size_t)(n0 + u) * HH + lane] = f2b(fmaxf(outv, 0.f));
    }
}

// ---------------- head via MFMA (h input is bf16) ----------------
__global__ __launch_bounds__(512) void k_head(const unsigned short* __restrict__ h,
                                              const float* __restrict__ W2,
                                              const float* __restrict__ b2,
                                              float* __restrict__ out) {
    __shared__ __align__(16) unsigned short hb[256][72];
    __shared__ float hf[256][65];
    __shared__ __align__(16) __hip_bfloat16 Bc[8][48][72];

    int tid = threadIdx.x;
    int lane = tid & 63;
    int w = tid >> 6;
    int nbase = blockIdx.x * 256;

#pragma unroll
    for (int p = 0; p < 32; ++p) {
        int idx = p * 512 + tid;
        int r = idx >> 6, c = idx & 63;
        int node = nbase + r;
        unsigned short raw = (node < NN) ? h[(size_t)node * HH + c] : 0;
        hf[r][c] = b2f(raw);
        hb[r][c] = raw;
    }
    for (int p = tid; p < 8 * 8 * 64; p += 512) {
        int il = p >> 9;
        int c = 40 + ((p >> 6) & 7);
        int jx = p & 63;
        Bc[il][c][jx] = __float2bfloat16(0.f);
    }

    f32x4 acc[2][3];
#pragma unroll
    for (int nf = 0; nf < 2; ++nf)
#pragma unroll
        for (int ct = 0; ct < 3; ++ct) acc[nf][ct] = (f32x4){0.f, 0.f, 0.f, 0.f};

    const f32x4 zf = (f32x4){0.f, 0.f, 0.f, 0.f};
    int arow0 = w * 32 + (lane & 15);
    int kq = (lane >> 4) * 8;
    int rb4 = w * 32 + ((lane >> 4) << 2);

    for (int ic = 0; ic < 8; ++ic) {
        __syncthreads();
#pragma unroll
        for (int p = 0; p < 10; ++p) {
            int q = p * 512 + tid;
            int cq = q % 10;
            int jj = (q / 10) & 63;
            int il = q / 640;
            const float4 v = *(const float4*)&W2[(((size_t)(ic * 8 + il) * 64 + jj) * CC) + cq * 4];
            Bc[il][cq * 4 + 0][jj] = __float2bfloat16(v.x);
            Bc[il][cq * 4 + 1][jj] = __float2bfloat16(v.y);
            Bc[il][cq * 4 + 2][jj] = __float2bfloat16(v.z);
            Bc[il][cq * 4 + 3][jj] = __float2bfloat16(v.w);
        }
        __syncthreads();

#pragma unroll
        for (int il = 0; il < 8; ++il) {
            int ii = ic * 8 + il;
            short8 a0k0 = *(const short8*)&hb[arow0][kq];
            short8 a0k1 = *(const short8*)&hb[arow0][32 + kq];
            short8 a1k0 = *(const short8*)&hb[arow0 + 16][kq];
            short8 a1k1 = *(const short8*)&hb[arow0 + 16][32 + kq];
            short8 b0k0 = *(const short8*)&Bc[il][(lane & 15)][kq];
            short8 b0k1 = *(const short8*)&Bc[il][(lane & 15)][32 + kq];
            short8 b1k0 = *(const short8*)&Bc[il][16 + (lane & 15)][kq];
            short8 b1k1 = *(const short8*)&Bc[il][16 + (lane & 15)][32 + kq];
            short8 b2k0 = *(const short8*)&Bc[il][32 + (lane & 15)][kq];
            short8 b2k1 = *(const short8*)&Bc[il][32 + (lane & 15)][32 + kq];
            float s0[4], s1[4];
#pragma unroll
            for (int r = 0; r < 4; ++r) {
                s0[r] = hf[rb4 + r][ii];
                s1[r] = hf[rb4 + 16 + r][ii];
            }
            f32x4 t;
            t = __builtin_amdgcn_mfma_f32_16x16x32_bf16(a0k0, b0k0, zf, 0, 0, 0);
            t = __builtin_amdgcn_mfma_f32_16x16x32_bf16(a0k1, b0k1, t, 0, 0, 0);
#pragma unroll
            for (int r = 0; r < 4; ++r) acc[0][0][r] = fmaf(s0[r], t[r], acc[0][0][r]);
            t = __builtin_amdgcn_mfma_f32_16x16x32_bf16(a0k0, b1k0, zf, 0, 0, 0);
            t = __builtin_amdgcn_mfma_f32_16x16x32_bf16(a0k1, b1k1, t, 0, 0, 0);
#pragma unroll
            for (int r = 0; r < 4; ++r) acc[0][1][r] = fmaf(s0[r], t[r], acc[0][1][r]);
            t = __builtin_amdgcn_mfma_f32_16x16x32_bf16(a0k0, b2k0, zf, 0, 0, 0);
            t = __builtin_amdgcn_mfma_f32_16x16x32_bf16(a0k1, b2k1, t, 0, 0, 0);
#pragma unroll
            for (int r = 0; r < 4; ++r) acc[0][2][r] = fmaf(s0[r], t[r], acc[0][2][r]);
            t = __builtin_amdgcn_mfma_f32_16x16x32_bf16(a1k0, b0k0, zf, 0, 0, 0);
            t = __builtin_amdgcn_mfma_f32_16x16x32_bf16(a1k1, b0k1, t, 0, 0, 0);
#pragma unroll
            for (int r = 0; r < 4; ++r) acc[1][0][r] = fmaf(s1[r], t[r], acc[1][0][r]);
            t = __builtin_amdgcn_mfma_f32_16x16x32_bf16(a1k0, b1k0, zf, 0, 0, 0);
            t = __builtin_amdgcn_mfma_f32_16x16x32_bf16(a1k1, b1k1, t, 0, 0, 0);
#pragma unroll
            for (int r = 0; r < 4; ++r) acc[1][1][r] = fmaf(s1[r], t[r], acc[1][1][r]);
            t = __builtin_amdgcn_mfma_f32_16x16x32_bf16(a1k0, b2k0, zf, 0, 0, 0);
            t = __builtin_amdgcn_mfma_f32_16x16x32_bf16(a1k1, b2k1, t, 0, 0, 0);
#pragma unroll
            for (int r = 0; r < 4; ++r) acc[1][2][r] = fmaf(s1[r], t[r], acc[1][2][r]);
        }
    }

#pragma unroll
    for (int nf = 0; nf < 2; ++nf) {
#pragma unroll
        for (int ct = 0; ct < 3; ++ct) {
            int c = ct * 16 + (lane & 15);
            if (c < CC) {
                float bias = b2[c];
#pragma unroll
                for (int r = 0; r < 4; ++r) {
                    int node = nbase + w * 32 + nf * 16 + ((lane >> 4) << 2) + r;
                    if (node < NN) out[(size_t)node * CC + c] = acc[nf][ct][r] + bias;
                }
            }
        }
    }
}

// ---------------- log_softmax in place, wave per node ----------------
__global__ void k_lsm(float* __restrict__ out) {
    int lane = threadIdx.x & 63;
    int n = (blockIdx.x * 256 + threadIdx.x) >> 6;
    if (n >= NN) return;
    float x = (lane < CC) ? out[(size_t)n * CC + lane] : -INFINITY;
    float m = x;
    for (int off = 32; off; off >>= 1) m = fmaxf(m, __shfl_xor(m, off));
    float e = (lane < CC) ? expf(x - m) : 0.f;
    float s = e;
    for (int off = 32; off; off >>= 1) s += __shfl_xor(s, off);
    float lse = m + logf(s);
    if (lane < CC) out[(size_t)n * CC + lane] = x - lse;
}

extern "C" void kernel_launch(void* const* d_in, const int* in_sizes, int n_in,
                              void* d_out, int out_size, void* d_ws, size_t ws_size,
                              hipStream_t stream) {
    const float* x  = (const float*)d_in[0];
    const int*   ei = (const int*)d_in[1];
    const float* ew = (const float*)d_in[2];
    const float* W0 = (const float*)d_in[3];
    const float* b0 = (const float*)d_in[4];
    const float* Wl = (const float*)d_in[5];
    const float* W2 = (const float*)d_in[6];
    const float* b2 = (const float*)d_in[7];
    float* out = (float*)d_out;

    char* ws = (char*)d_ws;
    size_t off = 0;
    auto alloc = [&](size_t b) { size_t o = off; off += (b + 255) & ~(size_t)255; return o; };
    float*          h0f = (float*)(ws + alloc((size_t)NN * HH * 4));
    unsigned short* h0b = (unsigned short*)(ws + alloc((size_t)NN * HH * 2));
    unsigned short* hA  = (unsigned short*)(ws + alloc((size_t)NN * HH * 2));
    unsigned short* hB  = (unsigned short*)(ws + alloc((size_t)NN * HH * 2));
    int*      cnt     = (int*)(ws + alloc((size_t)NN * 4));
    int*      incl    = (int*)(ws + alloc((size_t)NN * 4));
    int*      bsum    = (int*)(ws + alloc(256));
    int*      row_ptr = (int*)(ws + alloc((size_t)(NN + 1) * 4));
    int*      cursor  = (int*)(ws + alloc((size_t)NN * 4));
    unsigned* pay     = (unsigned*)(ws + alloc((size_t)EE * 4));

    const int* srcp = ei;
    const int* dstp = ei + EE;

    hipMemsetAsync(cnt, 0, (size_t)NN * 4, stream);
    k_hist<<<(EE + 255) / 256, 256, 0, stream>>>(dstp, cnt);
    k_scanA<<<49, 1024, 0, stream>>>(cnt, incl, bsum);
    k_scanB<<<1, 64, 0, stream>>>(bsum);
    k_scanC<<<49, 1024, 0, stream>>>(cnt, incl, bsum, row_ptr, cursor);
    k_scatter<<<(EE + 255) / 256, 256, 0, stream>>>(srcp, dstp, ew, cursor, pay);

    k_h0m<<<196, 512, 0, stream>>>(x, W0, b0, h0f, h0b);

    const unsigned short* hin = h0b;
    unsigned short* ho = hA;
    for (int l = 0; l < LL; l++) {
        float beta = (float)log(0.5 / (double)(l + 1) + 1.0);
        k_layer<<<3125, 256, 0, stream>>>(hin, h0f, row_ptr, pay,
                                          Wl + (size_t)l * HH * HH, beta, ho);
        hin = ho;
        ho = (ho == hA) ? hB : hA;
    }

    k_head<<<196, 512, 0, stream>>>(hin, W2, b2, out);
    k_lsm<<<(NN * 64 + 255) / 256, 256, 0, stream>>>(out);
}

// Round 9
// 550.854 us; speedup vs baseline: 1.1882x; 1.1344x over previous
//
#include <hip/hip_runtime.h>
#include <hip/hip_bf16.h>
#include <math.h>

#define NN 50000
#define FF 256
#define HH 64
#define LL 8
#define EE 1600000
#define CC 40

#define BK 64                       // dst nodes per bucket
#define NB ((NN + BK - 1) / BK)     // 782 buckets
#define PBK 4096                    // edges per partition block
#define NPART ((EE + PBK - 1) / PBK)

using short8 = __attribute__((ext_vector_type(8))) short;
using f32x4  = __attribute__((ext_vector_type(4))) float;

static __device__ __forceinline__ unsigned short f2b(float f) {
    union { __hip_bfloat16 h; unsigned short u; } cv;
    cv.h = __float2bfloat16(f);
    return cv.u;
}
static __device__ __forceinline__ float b2f(unsigned short u) {
    return __uint_as_float((unsigned)u << 16);
}

// ---------------- CSR build ----------------

__global__ void k_hist(const int* __restrict__ dst, int* __restrict__ cnt) {
    int e = blockIdx.x * 256 + threadIdx.x;
    if (e < EE) atomicAdd(&cnt[dst[e]], 1);
}

__global__ void k_scanA(const int* __restrict__ cnt, int* __restrict__ incl, int* __restrict__ bsum) {
    __shared__ int buf[1024];
    int i = blockIdx.x * 1024 + threadIdx.x;
    int v = (i < NN) ? cnt[i] : 0;
    buf[threadIdx.x] = v;
    __syncthreads();
    for (int off = 1; off < 1024; off <<= 1) {
        int t = (threadIdx.x >= off) ? buf[threadIdx.x - off] : 0;
        __syncthreads();
        buf[threadIdx.x] += t;
        __syncthreads();
    }
    if (i < NN) incl[i] = buf[threadIdx.x];
    if (threadIdx.x == 1023) bsum[blockIdx.x] = buf[1023];
}

__global__ void k_scanB(int* __restrict__ bsum) {
    int t = threadIdx.x;
    int vin = (t < 49) ? bsum[t] : 0;
    int v = vin;
    for (int off = 1; off < 64; off <<= 1) {
        int u = __shfl_up(v, off);
        if (t >= off) v += u;
    }
    if (t < 49) bsum[t] = v - vin;  // exclusive
}

__global__ void k_scanC(const int* __restrict__ cnt, const int* __restrict__ incl,
                        const int* __restrict__ bsum, int* __restrict__ row_ptr) {
    int i = blockIdx.x * 1024 + threadIdx.x;
    if (i < NN) row_ptr[i] = incl[i] - cnt[i] + bsum[blockIdx.x];
    if (i == 0) row_ptr[NN] = EE;
}

__global__ void k_binit(const int* __restrict__ row_ptr, int* __restrict__ bcur) {
    int t = blockIdx.x * 256 + threadIdx.x;
    if (t < NB) bcur[t] = row_ptr[t * BK];
}

// ---------------- pass 1: bucket partition (dst>>6), LDS-aggregated runs ----------------
__global__ void k_part(const int* __restrict__ src, const int* __restrict__ dst,
                       const float* __restrict__ w, int* __restrict__ bcur,
                       uint2* __restrict__ ebuk) {
    __shared__ int lh[NB];
    __shared__ int lbase[NB];
    int t = threadIdx.x;
    int e0 = blockIdx.x * PBK;
    int e1 = min(e0 + PBK, EE);
    for (int i = t; i < NB; i += 256) lh[i] = 0;
    __syncthreads();
    for (int e = e0 + t; e < e1; e += 256)
        atomicAdd(&lh[(unsigned)dst[e] >> 6], 1);
    __syncthreads();
    for (int i = t; i < NB; i += 256) {
        int c = lh[i];
        lbase[i] = c ? atomicAdd(&bcur[i], c) : 0;
    }
    __syncthreads();
    for (int i = t; i < NB; i += 256) lh[i] = 0;
    __syncthreads();
    for (int e = e0 + t; e < e1; e += 256) {
        int d = dst[e];
        int b = (unsigned)d >> 6;
        int r = atomicAdd(&lh[b], 1);
        ebuk[lbase[b] + r] = make_uint2(((unsigned)src[e] << 16) | (unsigned)f2b(w[e]),
                                        (unsigned)d);
    }
}

// ---------------- pass 2: per-bucket local scatter into contiguous pay region ----------------
__global__ void k_sub(const int* __restrict__ row_ptr, const uint2* __restrict__ ebuk,
                      unsigned* __restrict__ pay) {
    __shared__ int lcur[BK];
    int b = blockIdx.x;
    int d0 = b * BK;
    int t = threadIdx.x;
    if (t < BK && d0 + t < NN) lcur[t] = row_ptr[d0 + t];
    __syncthreads();
    int lo = row_ptr[d0];
    int hi = row_ptr[min(d0 + BK, NN)];
    for (int i = lo + t; i < hi; i += 256) {
        uint2 pk = ebuk[i];
        int p = atomicAdd(&lcur[pk.y - d0], 1);
        pay[p] = pk.x;
    }
}

// ---------------- initial projection via MFMA: h0 = relu(x @ W0 + b0) ----------------
__global__ __launch_bounds__(512) void k_h0m(const float* __restrict__ x,
                                             const float* __restrict__ W0,
                                             const float* __restrict__ b0,
                                             float* __restrict__ h0f,
                                             unsigned short* __restrict__ h0b) {
    __shared__ __align__(16) __hip_bfloat16 ax[256][72];
    __shared__ __align__(16) __hip_bfloat16 bw[64][72];

    int tid = threadIdx.x;
    int lane = tid & 63;
    int w = tid >> 6;
    int nbase = blockIdx.x * 256;

    f32x4 acc[2][4];
#pragma unroll
    for (int nf = 0; nf < 2; ++nf)
#pragma unroll
        for (int cf = 0; cf < 4; ++cf) acc[nf][cf] = (f32x4){0.f, 0.f, 0.f, 0.f};

    int arow = w * 32 + (lane & 15);
    int kq = (lane >> 4) * 8;

    for (int kc = 0; kc < 4; ++kc) {
        __syncthreads();
#pragma unroll
        for (int p = 0; p < 8; ++p) {
            int q = p * 512 + tid;
            int r = q >> 4, cq = q & 15;
            int node = nbase + r;
            float4 v = {0.f, 0.f, 0.f, 0.f};
            if (node < NN) v = *(const float4*)&x[(size_t)node * FF + kc * 64 + cq * 4];
            __hip_bfloat16* d = &ax[r][cq * 4];
            d[0] = __float2bfloat16(v.x);
            d[1] = __float2bfloat16(v.y);
            d[2] = __float2bfloat16(v.z);
            d[3] = __float2bfloat16(v.w);
        }
#pragma unroll
        for (int u = 0; u < 8; ++u) {
            int k = (tid >> 6) * 8 + u;
            float v = W0[(size_t)(kc * 64 + k) * HH + lane];
            bw[lane][k] = __float2bfloat16(v);
        }
        __syncthreads();
#pragma unroll
        for (int ks = 0; ks < 2; ++ks) {
            short8 a0 = *(const short8*)&ax[arow][ks * 32 + kq];
            short8 a1 = *(const short8*)&ax[arow + 16][ks * 32 + kq];
#pragma unroll
            for (int cf = 0; cf < 4; ++cf) {
                short8 b = *(const short8*)&bw[cf * 16 + (lane & 15)][ks * 32 + kq];
                acc[0][cf] = __builtin_amdgcn_mfma_f32_16x16x32_bf16(a0, b, acc[0][cf], 0, 0, 0);
                acc[1][cf] = __builtin_amdgcn_mfma_f32_16x16x32_bf16(a1, b, acc[1][cf], 0, 0, 0);
            }
        }
    }

#pragma unroll
    for (int nf = 0; nf < 2; ++nf) {
#pragma unroll
        for (int cf = 0; cf < 4; ++cf) {
            int c = cf * 16 + (lane & 15);
            float bias = b0[c];
#pragma unroll
            for (int r = 0; r < 4; ++r) {
                int node = nbase + w * 32 + nf * 16 + ((lane >> 4) << 2) + r;
                if (node < NN) {
                    float v = fmaxf(acc[nf][cf][r] + bias, 0.f);
                    h0f[(size_t)node * HH + c] = v;
                    h0b[(size_t)node * HH + c] = f2b(v);
                }
            }
        }
    }
}

// ---------------- fused layer: paired-edge bf16x2 SpMM + blend + matvec + relu ----------------
__global__ __launch_bounds__(256, 8) void k_layer(
        const unsigned short* __restrict__ hin, const float* __restrict__ h0,
        const int* __restrict__ row_ptr, const unsigned* __restrict__ pay,
        const float* __restrict__ Wl, float beta,
        unsigned short* __restrict__ hout) {
    int lane = threadIdx.x & 63;
    int half = lane >> 5;
    int j = lane & 31;                 // channel pair (2j, 2j+1)
    int n0 = (blockIdx.x * 4 + (threadIdx.x >> 6)) * 4;

    const unsigned* __restrict__ hin32 = (const unsigned*)hin;

    float hmix[4];
#pragma unroll
    for (int u = 0; u < 4; ++u) {
        int n = n0 + u;
        int rb = row_ptr[n], re = row_ptr[n + 1];
        float ax0 = 0.f, ay0 = 0.f, ax1 = 0.f, ay1 = 0.f;
        for (int base = rb; base < re; base += 64) {
            int idx = base + lane;
            unsigned pv = (idx < re) ? pay[idx] : 0u;  // pad: src=0, w=+0
            int ecnt = min(64, re - base);
            for (int k = 0; k < ecnt; k += 8) {
                unsigned pk[8];
#pragma unroll
                for (int t = 0; t < 8; t++)
                    pk[t] = (unsigned)__builtin_amdgcn_readlane((int)pv, k + t);
                unsigned m0 = half ? pk[1] : pk[0];
                unsigned m1 = half ? pk[3] : pk[2];
                unsigned m2 = half ? pk[5] : pk[4];
                unsigned m3 = half ? pk[7] : pk[6];
                unsigned u0 = hin32[(size_t)(m0 >> 16) * 32 + j];
                unsigned u1 = hin32[(size_t)(m1 >> 16) * 32 + j];
                unsigned u2 = hin32[(size_t)(m2 >> 16) * 32 + j];
                unsigned u3 = hin32[(size_t)(m3 >> 16) * 32 + j];
                float w0 = __uint_as_float((m0 & 0xFFFFu) << 16);
                float w1 = __uint_as_float((m1 & 0xFFFFu) << 16);
                float w2 = __uint_as_float((m2 & 0xFFFFu) << 16);
                float w3 = __uint_as_float((m3 & 0xFFFFu) << 16);
                ax0 = fmaf(w0, __uint_as_float(u0 << 16), ax0);
                ay0 = fmaf(w0, __uint_as_float(u0 & 0xFFFF0000u), ay0);
                ax1 = fmaf(w1, __uint_as_float(u1 << 16), ax1);
                ay1 = fmaf(w1, __uint_as_float(u1 & 0xFFFF0000u), ay1);
                ax0 = fmaf(w2, __uint_as_float(u2 << 16), ax0);
                ay0 = fmaf(w2, __uint_as_float(u2 & 0xFFFF0000u), ay0);
                ax1 = fmaf(w3, __uint_as_float(u3 << 16), ax1);
                ay1 = fmaf(w3, __uint_as_float(u3 & 0xFFFF0000u), ay1);
            }
        }
        float ax = ax0 + ax1, ay = ay0 + ay1;
        ax += __shfl_xor(ax, 32);       // combine even/odd halves
        ay += __shfl_xor(ay, 32);
        float vx = __shfl(ax, lane >> 1);
        float vy = __shfl(ay, lane >> 1);
        float acc = (lane & 1) ? vy : vx;
        hmix[u] = fmaf(0.9f, acc, 0.1f * h0[(size_t)n * HH + lane]);
    }

    int hb[4];
#pragma unroll
    for (int u = 0; u < 4; ++u) hb[u] = __float_as_int(hmix[u]);
    float a2[4] = {0.f, 0.f, 0.f, 0.f};
#pragma unroll
    for (int jj = 0; jj < HH; jj++) {
        float wr = Wl[jj * HH + lane];
#pragma unroll
        for (int u = 0; u < 4; ++u) {
            float hj = __int_as_float(__builtin_amdgcn_readlane(hb[u], jj));
            a2[u] = fmaf(hj, wr, a2[u]);
        }
    }
#pragma unroll
    for (int u = 0; u < 4; ++u) {
        float outv = (1.f - beta) * hmix[u] + beta * a2[u];
        hout[(size_t)(n0 + u) * HH + lane] = f2b(fmaxf(outv, 0.f));
    }
}

// ---------------- head via MFMA (h input is bf16) ----------------
__global__ __launch_bounds__(512) void k_head(const unsigned short* __restrict__ h,
                                              const float* __restrict__ W2,
                                              const float* __restrict__ b2,
                                              float* __restrict__ out) {
    __shared__ __align__(16) unsigned short hb[256][72];
    __shared__ float hf[256][65];
    __shared__ __align__(16) __hip_bfloat16 Bc[8][48][72];

    int tid = threadIdx.x;
    int lane = tid & 63;
    int w = tid >> 6;
    int nbase = blockIdx.x * 256;

#pragma unroll
    for (int p = 0; p < 32; ++p) {
        int idx = p * 512 + tid;
        int r = idx >> 6, c = idx & 63;
        int node = nbase + r;
        unsigned short raw = (node < NN) ? h[(size_t)node * HH + c] : 0;
        hf[r][c] = b2f(raw);
        hb[r][c] = raw;
    }
    for (int p = tid; p < 8 * 8 * 64; p += 512) {
        int il = p >> 9;
        int c = 40 + ((p >> 6) & 7);
        int jx = p & 63;
        Bc[il][c][jx] = __float2bfloat16(0.f);
    }

    f32x4 acc[2][3];
#pragma unroll
    for (int nf = 0; nf < 2; ++nf)
#pragma unroll
        for (int ct = 0; ct < 3; ++ct) acc[nf][ct] = (f32x4){0.f, 0.f, 0.f, 0.f};

    const f32x4 zf = (f32x4){0.f, 0.f, 0.f, 0.f};
    int arow0 = w * 32 + (lane & 15);
    int kq = (lane >> 4) * 8;
    int rb4 = w * 32 + ((lane >> 4) << 2);

    for (int ic = 0; ic < 8; ++ic) {
        __syncthreads();
#pragma unroll
        for (int p = 0; p < 10; ++p) {
            int q = p * 512 + tid;
            int cq = q % 10;
            int jj = (q / 10) & 63;
            int il = q / 640;
            const float4 v = *(const float4*)&W2[(((size_t)(ic * 8 + il) * 64 + jj) * CC) + cq * 4];
            Bc[il][cq * 4 + 0][jj] = __float2bfloat16(v.x);
            Bc[il][cq * 4 + 1][jj] = __float2bfloat16(v.y);
            Bc[il][cq * 4 + 2][jj] = __float2bfloat16(v.z);
            Bc[il][cq * 4 + 3][jj] = __float2bfloat16(v.w);
        }
        __syncthreads();

#pragma unroll
        for (int il = 0; il < 8; ++il) {
            int ii = ic * 8 + il;
            short8 a0k0 = *(const short8*)&hb[arow0][kq];
            short8 a0k1 = *(const short8*)&hb[arow0][32 + kq];
            short8 a1k0 = *(const short8*)&hb[arow0 + 16][kq];
            short8 a1k1 = *(const short8*)&hb[arow0 + 16][32 + kq];
            short8 b0k0 = *(const short8*)&Bc[il][(lane & 15)][kq];
            short8 b0k1 = *(const short8*)&Bc[il][(lane & 15)][32 + kq];
            short8 b1k0 = *(const short8*)&Bc[il][16 + (lane & 15)][kq];
            short8 b1k1 = *(const short8*)&Bc[il][16 + (lane & 15)][32 + kq];
            short8 b2k0 = *(const short8*)&Bc[il][32 + (lane & 15)][kq];
            short8 b2k1 = *(const short8*)&Bc[il][32 + (lane & 15)][32 + kq];
            float s0[4], s1[4];
#pragma unroll
            for (int r = 0; r < 4; ++r) {
                s0[r] = hf[rb4 + r][ii];
                s1[r] = hf[rb4 + 16 + r][ii];
            }
            f32x4 t;
            t = __builtin_amdgcn_mfma_f32_16x16x32_bf16(a0k0, b0k0, zf, 0, 0, 0);
            t = __builtin_amdgcn_mfma_f32_16x16x32_bf16(a0k1, b0k1, t, 0, 0, 0);
#pragma unroll
            for (int r = 0; r < 4; ++r) acc[0][0][r] = fmaf(s0[r], t[r], acc[0][0][r]);
            t = __builtin_amdgcn_mfma_f32_16x16x32_bf16(a0k0, b1k0, zf, 0, 0, 0);
            t = __builtin_amdgcn_mfma_f32_16x16x32_bf16(a0k1, b1k1, t, 0, 0, 0);
#pragma unroll
            for (int r = 0; r < 4; ++r) acc[0][1][r] = fmaf(s0[r], t[r], acc[0][1][r]);
            t = __builtin_amdgcn_mfma_f32_16x16x32_bf16(a0k0, b2k0, zf, 0, 0, 0);
            t = __builtin_amdgcn_mfma_f32_16x16x32_bf16(a0k1, b2k1, t, 0, 0, 0);
#pragma unroll
            for (int r = 0; r < 4; ++r) acc[0][2][r] = fmaf(s0[r], t[r], acc[0][2][r]);
            t = __builtin_amdgcn_mfma_f32_16x16x32_bf16(a1k0, b0k0, zf, 0, 0, 0);
            t = __builtin_amdgcn_mfma_f32_16x16x32_bf16(a1k1, b0k1, t, 0, 0, 0);
#pragma unroll
            for (int r = 0; r < 4; ++r) acc[1][0][r] = fmaf(s1[r], t[r], acc[1][0][r]);
            t = __builtin_amdgcn_mfma_f32_16x16x32_bf16(a1k0, b1k0, zf, 0, 0, 0);
            t = __builtin_amdgcn_mfma_f32_16x16x32_bf16(a1k1, b1k1, t, 0, 0, 0);
#pragma unroll
            for (int r = 0; r < 4; ++r) acc[1][1][r] = fmaf(s1[r], t[r], acc[1][1][r]);
            t = __builtin_amdgcn_mfma_f32_16x16x32_bf16(a1k0, b2k0, zf, 0, 0, 0);
            t = __builtin_amdgcn_mfma_f32_16x16x32_bf16(a1k1, b2k1, t, 0, 0, 0);
#pragma unroll
            for (int r = 0; r < 4; ++r) acc[1][2][r] = fmaf(s1[r], t[r], acc[1][2][r]);
        }
    }

#pragma unroll
    for (int nf = 0; nf < 2; ++nf) {
#pragma unroll
        for (int ct = 0; ct < 3; ++ct) {
            int c = ct * 16 + (lane & 15);
            if (c < CC) {
                float bias = b2[c];
#pragma unroll
                for (int r = 0; r < 4; ++r) {
                    int node = nbase + w * 32 + nf * 16 + ((lane >> 4) << 2) + r;
                    if (node < NN) out[(size_t)node * CC + c] = acc[nf][ct][r] + bias;
                }
            }
        }
    }
}

// ---------------- log_softmax in place, wave per node ----------------
__global__ void k_lsm(float* __restrict__ out) {
    int lane = threadIdx.x & 63;
    int n = (blockIdx.x * 256 + threadIdx.x) >> 6;
    if (n >= NN) return;
    float x = (lane < CC) ? out[(size_t)n * CC + lane] : -INFINITY;
    float m = x;
    for (int off = 32; off; off >>= 1) m = fmaxf(m, __shfl_xor(m, off));
    float e = (lane < CC) ? expf(x - m) : 0.f;
    float s = e;
    for (int off = 32; off; off >>= 1) s += __shfl_xor(s, off);
    float lse = m + logf(s);
    if (lane < CC) out[(size_t)n * CC + lane] = x - lse;
}

extern "C" void kernel_launch(void* const* d_in, const int* in_sizes, int n_in,
                              void* d_out, int out_size, void* d_ws, size_t ws_size,
                              hipStream_t stream) {
    const float* x  = (const float*)d_in[0];
    const int*   ei = (const int*)d_in[1];
    const float* ew = (const float*)d_in[2];
    const float* W0 = (const float*)d_in[3];
    const float* b0 = (const float*)d_in[4];
    const float* Wl = (const float*)d_in[5];
    const float* W2 = (const float*)d_in[6];
    const float* b2 = (const float*)d_in[7];
    float* out = (float*)d_out;

    char* ws = (char*)d_ws;
    size_t off = 0;
    auto alloc = [&](size_t b) { size_t o = off; off += (b + 255) & ~(size_t)255; return o; };
    float*          h0f = (float*)(ws + alloc((size_t)NN * HH * 4));
    unsigned short* h0b = (unsigned short*)(ws + alloc((size_t)NN * HH * 2));
    unsigned short* hA  = (unsigned short*)(ws + alloc((size_t)NN * HH * 2));
    unsigned short* hB  = (unsigned short*)(ws + alloc((size_t)NN * HH * 2));
    int*      cnt     = (int*)(ws + alloc((size_t)NN * 4));
    int*      incl    = (int*)(ws + alloc((size_t)NN * 4));
    int*      bsum    = (int*)(ws + alloc(256));
    int*      row_ptr = (int*)(ws + alloc((size_t)(NN + 1) * 4));
    int*      bcur    = (int*)(ws + alloc((size_t)NB * 4));
    uint2*    ebuk    = (uint2*)(ws + alloc((size_t)EE * 8));
    unsigned* pay     = (unsigned*)(ws + alloc((size_t)EE * 4));

    const int* srcp = ei;
    const int* dstp = ei + EE;

    hipMemsetAsync(cnt, 0, (size_t)NN * 4, stream);
    k_hist<<<(EE + 255) / 256, 256, 0, stream>>>(dstp, cnt);
    k_scanA<<<49, 1024, 0, stream>>>(cnt, incl, bsum);
    k_scanB<<<1, 64, 0, stream>>>(bsum);
    k_scanC<<<49, 1024, 0, stream>>>(cnt, incl, bsum, row_ptr);
    k_binit<<<(NB + 255) / 256, 256, 0, stream>>>(row_ptr, bcur);
    k_part<<<NPART, 256, 0, stream>>>(srcp, dstp, ew, bcur, ebuk);
    k_sub<<<NB, 256, 0, stream>>>(row_ptr, ebuk, pay);

    k_h0m<<<196, 512, 0, stream>>>(x, W0, b0, h0f, h0b);

    const unsigned short* hin = h0b;
    unsigned short* ho = hA;
    for (int l = 0; l < LL; l++) {
        float beta = (float)log(0.5 / (double)(l + 1) + 1.0);
        k_layer<<<3125, 256, 0, stream>>>(hin, h0f, row_ptr, pay,
                                          Wl + (size_t)l * HH * HH, beta, ho);
        hin = ho;
        ho = (ho == hA) ? hB : hA;
    }

    k_head<<<196, 512, 0, stream>>>(hin, W2, b2, out);
    k_lsm<<<(NN * 64 + 255) / 256, 256, 0, stream>>>(out);
}